// Round 6
// baseline (176.756 us; speedup 1.0000x reference)
//
#include <hip/hip_runtime.h>
#include <hip/hip_bf16.h>

// Spalize: out0[k,c,h,w] = img[c,h,w] * (mask[h,w]==k); out1 = mask (as float).
// K=50, C=3, H=W=512. 157 MB output.
// R0-R5: four structurally different kernels (1 wave/SIMD strided; split-K
// 10x TLP; linear sweep; linear sweep + nt stores) ALL land at 157-161us
// total. Hypothesis: the timed window is dominated by fixed harness work
// (633MB ws poison ~94us + 158MB out poison ~25us + restores/gaps) and the
// kernel is ALREADY near the ~26us write roofline.
// R6 PROBE: launch the kernel TWICE (idempotent, graph-safe). The dur_us
// delta vs 157us measures one kernel invocation in-band:
//   ~+27us -> kernel at roofline, revert & declare; ~+60us -> real problem.

#define K  50
#define C  3
#define H  512
#define W  512
#define HW (H * W)                 // 262144
#define OUT0 (K * C * HW)          // 39,321,600 floats
#define OUT_TOTAL (OUT0 + HW)      // 39,583,744 floats
#define BLOCK 256

__global__ __launch_bounds__(BLOCK) void spalize_kernel(
    const float* __restrict__ img,   // [C,H,W]
    const int*   __restrict__ mask,  // [H,W] int32
    float*       __restrict__ out)   // [K,C,H,W] then [H,W] mask-as-float
{
    const int tid = blockIdx.x * BLOCK + threadIdx.x;
    const int f = tid * 4;           // flat output float index

    if (f < OUT0) {
        const int plane = f >> 18;          // f / HW  (wave-uniform)
        const int p     = f & (HW - 1);     // pixel index
        const int k     = (plane * 0x5556) >> 16;  // plane / 3 (plane < 150)
        const int c     = plane - k * 3;

        const int4   m = *reinterpret_cast<const int4*>(mask + p);
        const float4 a = *reinterpret_cast<const float4*>(img + c * HW + p);

        float4 o;
        o.x = (m.x == k) ? a.x : 0.0f;
        o.y = (m.y == k) ? a.y : 0.0f;
        o.z = (m.z == k) ? a.z : 0.0f;
        o.w = (m.w == k) ? a.w : 0.0f;
        *reinterpret_cast<float4*>(out + f) = o;
    } else {
        const int p = f - OUT0;             // mask pass-through
        const int4 m = *reinterpret_cast<const int4*>(mask + p);
        float4 mf;
        mf.x = (float)m.x; mf.y = (float)m.y;
        mf.z = (float)m.z; mf.w = (float)m.w;
        *reinterpret_cast<float4*>(out + f) = mf;
    }
}

extern "C" void kernel_launch(void* const* d_in, const int* in_sizes, int n_in,
                              void* d_out, int out_size, void* d_ws, size_t ws_size,
                              hipStream_t stream) {
    const float* img  = (const float*)d_in[0];
    const int*   mask = (const int*)d_in[1];
    float*       out  = (float*)d_out;

    const int nthreads = OUT_TOTAL / 4;          // 9,895,936
    const int grid = nthreads / BLOCK;           // 38,656 blocks (exact)
    // PROBE: two identical launches; delta vs single-launch dur_us measures
    // one kernel invocation (idempotent -> output unchanged).
    spalize_kernel<<<grid, BLOCK, 0, stream>>>(img, mask, out);
    spalize_kernel<<<grid, BLOCK, 0, stream>>>(img, mask, out);
}

// Round 7
// 156.523 us; speedup vs baseline: 1.1293x; 1.1293x over previous
//
#include <hip/hip_runtime.h>
#include <hip/hip_bf16.h>

// Spalize: out0[k,c,h,w] = img[c,h,w] * (mask[h,w]==k); out1 = mask (as float).
// K=50, C=3, H=W=512. 157 MB output, 4 MB input.
//
// FINAL (R7): linear-sweep structure, one thread per 4 consecutive output
// floats, all loads/stores 16 B/lane coalesced. Wave-uniform (k,c) plane
// (HW % 256 == 0); mask/img reads L2-resident across the 50x re-read.
//
// ROOFLINE EVIDENCE (R6 double-launch probe): dur_us 157.1 -> 176.8 with a
// second identical launch => ONE kernel invocation ~= 19.7 us, at/below the
// 157 MB / 6.3 TB/s ~= 25 us achievable-write floor. The remaining ~137 us of
// the timed window is fixed harness work (633 MB 0xAA poison fills at ~94 us
// + d_out poison + input restores), outside kernel control. R1 (10x TLP),
// R2 (write-order), R3/R5 (nt stores) all moved nothing because the kernel
// term was already ~20 us — sub-noise inside a ~157 us window.

#define K  50
#define C  3
#define H  512
#define W  512
#define HW (H * W)                 // 262144
#define OUT0 (K * C * HW)          // 39,321,600 floats
#define OUT_TOTAL (OUT0 + HW)      // 39,583,744 floats
#define BLOCK 256

__global__ __launch_bounds__(BLOCK) void spalize_kernel(
    const float* __restrict__ img,   // [C,H,W]
    const int*   __restrict__ mask,  // [H,W] int32
    float*       __restrict__ out)   // [K,C,H,W] then [H,W] mask-as-float
{
    const int tid = blockIdx.x * BLOCK + threadIdx.x;
    const int f = tid * 4;           // flat output float index

    if (f < OUT0) {
        const int plane = f >> 18;          // f / HW  (wave-uniform)
        const int p     = f & (HW - 1);     // pixel index
        const int k     = (plane * 0x5556) >> 16;  // plane / 3 (plane < 150)
        const int c     = plane - k * 3;

        const int4   m = *reinterpret_cast<const int4*>(mask + p);
        const float4 a = *reinterpret_cast<const float4*>(img + c * HW + p);

        float4 o;
        o.x = (m.x == k) ? a.x : 0.0f;
        o.y = (m.y == k) ? a.y : 0.0f;
        o.z = (m.z == k) ? a.z : 0.0f;
        o.w = (m.w == k) ? a.w : 0.0f;
        *reinterpret_cast<float4*>(out + f) = o;
    } else {
        const int p = f - OUT0;             // mask pass-through
        const int4 m = *reinterpret_cast<const int4*>(mask + p);
        float4 mf;
        mf.x = (float)m.x; mf.y = (float)m.y;
        mf.z = (float)m.z; mf.w = (float)m.w;
        *reinterpret_cast<float4*>(out + f) = mf;
    }
}

extern "C" void kernel_launch(void* const* d_in, const int* in_sizes, int n_in,
                              void* d_out, int out_size, void* d_ws, size_t ws_size,
                              hipStream_t stream) {
    const float* img  = (const float*)d_in[0];
    const int*   mask = (const int*)d_in[1];
    float*       out  = (float*)d_out;

    const int nthreads = OUT_TOTAL / 4;          // 9,895,936
    const int grid = nthreads / BLOCK;           // 38,656 blocks (exact)
    spalize_kernel<<<grid, BLOCK, 0, stream>>>(img, mask, out);
}